// Round 3
// baseline (1147.938 us; speedup 1.0000x reference)
//
#include <hip/hip_runtime.h>

// 2-layer LSTM, B=2048, T=4096, IN=1, H=8, OUT=1, fp32.
//
// Quad layout within each 32-lane group (= one sequence; 2 seq/wave):
//   lane = j*4 + L*2 + p    j=unit(bits2..4), L=layer(bit1), p=k-half(bit0)
// Each lane holds all 4 gate rows (i,f,g,o) of unit j, layer L, but only
// k in {j^ (4p+0..3)} (4 of 8). Pair totals combined via quad_perm xor1 DPP.
// Cross-lane:
//   - pair combine + activation share: quad_perm[1,0,3,2] (involutive DPP)
//   - h gather: 8 ds_bpermute with per-lane precomputed xor addresses
//     (own-layer 4 + other-layer 4), issued once per step right after h.
// Layer pipeline: iter t computes L0(t) and L1(t-1), both from the gather
// at the end of iter t-1. Projection rides L0's spare second-dot slot.
// Gate pre-scale: sigma rows x(-log2e), tanh row x(-2log2e) so activation
// is rcp(1+exp2(z)) (+ fma for tanh).

constexpr int Bsz = 2048;
constexpr int Tsz = 4096;

__device__ __forceinline__ float dpp_xor1(float v) {
    // quad_perm [1,0,3,2] = lane^1, involutive
    return __int_as_float(
        __builtin_amdgcn_mov_dpp(__float_as_int(v), 0xB1, 0xF, 0xF, true));
}

__device__ __forceinline__ float bperm(int addr, float v) {
    return __int_as_float(
        __builtin_amdgcn_ds_bpermute(addr, __float_as_int(v)));
}

__global__ void __launch_bounds__(256) lstm2_quad(
    const float* __restrict__ x,      // [B, T]
    const float* __restrict__ Wih0,   // [32, 1]
    const float* __restrict__ Whh0,   // [32, 8]
    const float* __restrict__ bih0,   // [32]
    const float* __restrict__ bhh0,   // [32]
    const float* __restrict__ Wih1,   // [32, 8]
    const float* __restrict__ Whh1,   // [32, 8]
    const float* __restrict__ bih1,   // [32]
    const float* __restrict__ bhh1,   // [32]
    const float* __restrict__ Wlin,   // [1, 8]
    const float* __restrict__ blin,   // [1]
    float* __restrict__ out)          // [B, T]
{
    const int tid   = threadIdx.x;
    const int lane  = tid & 63;
    const int l32   = tid & 31;
    const int p     = l32 & 1;
    const int L     = (l32 >> 1) & 1;
    const int j     = (l32 >> 2) & 7;
    const bool pb   = (p != 0);
    const int seq   = blockIdx.x * 8 + (tid >> 5);

    const float NL2E  = -1.4426950408889634f;   // -log2(e)
    const float N2L2E = -2.8853900817779268f;   // -2*log2(e)
    const float sr[4] = { NL2E, NL2E, N2L2E, NL2E };  // i,f,g(tanh),o
    const float sA = pb ? 2.0f : 1.0f;   // p=1 activates tanh row (g)
    const float oA = pb ? -1.0f : 0.0f;

    const float* __restrict__ Whh = L ? Whh1 : Whh0;
    const float* __restrict__ bih = L ? bih1 : bih0;
    const float* __restrict__ bhh = L ? bhh1 : bhh0;

    float whh[4][4], wzx[4][4], bzh[4], wxh[4];
#pragma unroll
    for (int r = 0; r < 4; ++r) {
        const int row = r * 8 + j;
        bzh[r] = 0.5f * (bih[row] + bhh[row]) * sr[r];   // half on each p
        wxh[r] = L ? 0.0f : 0.5f * Wih0[row] * sr[r];    // half on each p
#pragma unroll
        for (int i = 0; i < 4; ++i) {
            const int k = j ^ (p * 4 + i);
            whh[r][i] = Whh[row * 8 + k] * sr[r];
            wzx[r][i] = L ? (Wih1[row * 8 + k] * sr[r])
                          : (r == 0 ? Wlin[k] : 0.0f);
        }
    }
    const float bxh = L ? 0.0f : 0.5f * blin[0];  // proj bias, half per p
    const float mL  = L ? 1.0f : 0.0f;            // merge 2nd dot only on L1
    const float keep = 1.0f - mL;

    // bpermute addresses (bytes): own-layer then other-layer pulls
    int addrh[4], addrx[4];
#pragma unroll
    for (int i = 0; i < 4; ++i) {
        const int m = 4 * (p * 4 + i);
        addrh[i] = (lane ^ m) * 4;
        addrx[i] = (lane ^ m ^ 2) * 4;
    }

    const float* __restrict__ xp = x + (size_t)seq * Tsz;
    float* __restrict__ op       = out + (size_t)seq * Tsz;
    const bool lane0 = (l32 == 0);

    float hh[4], hx[4];
#pragma unroll
    for (int i = 0; i < 4; ++i) { hh[i] = 0.0f; hx[i] = 0.0f; }
    float c = 0.0f, h = 0.0f, proj = 0.0f;

    auto cellstep = [&](float xt) {
        float ph[4], px[4];
#pragma unroll
        for (int r = 0; r < 4; ++r) ph[r] = fmaf(wxh[r], xt, bzh[r]);
        px[0] = bxh; px[1] = 0.0f; px[2] = 0.0f; px[3] = 0.0f;
#pragma unroll
        for (int i = 0; i < 4; ++i) {
#pragma unroll
            for (int r = 0; r < 4; ++r) {
                ph[r] = fmaf(whh[r][i], hh[i], ph[r]);
                px[r] = fmaf(wzx[r][i], hx[i], px[r]);
            }
        }
        float z[4], zx[4];
#pragma unroll
        for (int r = 0; r < 4; ++r) z[r]  = ph[r] + dpp_xor1(ph[r]);
#pragma unroll
        for (int r = 0; r < 4; ++r) zx[r] = px[r] + dpp_xor1(px[r]);
#pragma unroll
        for (int r = 0; r < 4; ++r) z[r] = fmaf(zx[r], mL, z[r]);

        // p=0 activates rows i,f; p=1 activates rows g(tanh),o
        const float zSa = pb ? z[2] : z[0];
        const float zSb = pb ? z[3] : z[1];
        float aA = fmaf(sA,
                        __builtin_amdgcn_rcpf(1.0f + __builtin_amdgcn_exp2f(zSa)),
                        oA);
        float aB = __builtin_amdgcn_rcpf(1.0f + __builtin_amdgcn_exp2f(zSb));
        const float rA = dpp_xor1(aA);
        const float rB = dpp_xor1(aB);
        const float gi = pb ? rA : aA;
        const float gf = pb ? rB : aB;
        const float gg = pb ? aA : rA;
        const float go = pb ? aB : rB;
        c = fmaf(gf, c, gi * gg);
        const float e  = __builtin_amdgcn_exp2f(c * N2L2E);
        const float th = fmaf(2.0f, __builtin_amdgcn_rcpf(1.0f + e), -1.0f);
        h = go * th;
        proj = zx[0];   // L0 lanes: blin + Wlin . h2(t-2)
    };

    auto gather = [&]() {
        // one batch of 8 bpermutes; own-layer first (needed first)
        hh[0] = bperm(addrh[0], h);
        hh[1] = bperm(addrh[1], h);
        hh[2] = bperm(addrh[2], h);
        hh[3] = bperm(addrh[3], h);
        hx[0] = bperm(addrx[0], h);
        hx[1] = bperm(addrx[1], h);
        hx[2] = bperm(addrx[2], h);
        hx[3] = bperm(addrx[3], h);
    };

    // ---- peel t=0: L0 computes h1(0); L1 result discarded ----
    cellstep(xp[0]);
    h *= keep;   // zero L1 state (h2(-1)=0, c2(-1)=0)
    c *= keep;
    gather();

    // ---- main loop: iter t computes L0(t) and L1(t-1) ----
    float xn1 = xp[1];
    float xn2 = xp[2];
    for (int t = 1; t <= Tsz + 1; ++t) {
        const float xt = xn1;
        xn1 = xn2;
        int ti = t + 2; ti = (ti < Tsz) ? ti : (Tsz - 1);
        xn2 = xp[ti];

        cellstep(xt);
        if (t >= 2 && lane0) op[t - 2] = proj;
        gather();
    }
}

extern "C" void kernel_launch(void* const* d_in, const int* in_sizes, int n_in,
                              void* d_out, int out_size, void* d_ws, size_t ws_size,
                              hipStream_t stream) {
    const float* x    = (const float*)d_in[0];
    const float* Wih0 = (const float*)d_in[1];
    const float* Whh0 = (const float*)d_in[2];
    const float* bih0 = (const float*)d_in[3];
    const float* bhh0 = (const float*)d_in[4];
    const float* Wih1 = (const float*)d_in[5];
    const float* Whh1 = (const float*)d_in[6];
    const float* bih1 = (const float*)d_in[7];
    const float* bhh1 = (const float*)d_in[8];
    const float* Wlin = (const float*)d_in[9];
    const float* blin = (const float*)d_in[10];
    float* out = (float*)d_out;

    dim3 grid(Bsz / 8);   // 8 sequences per 256-thread block (2 per wave)
    dim3 block(256);
    hipLaunchKernelGGL(lstm2_quad, grid, block, 0, stream,
                       x, Wih0, Whh0, bih0, bhh0,
                       Wih1, Whh1, bih1, bhh1, Wlin, blin, out);
}

// Round 4
// 1004.249 us; speedup vs baseline: 1.1431x; 1.1431x over previous
//
#include <hip/hip_runtime.h>

// 2-layer LSTM, B=2048, T=4096, IN=1, H=8, OUT=1, fp32.
//
// Lane layout (32 lanes/seq, 2 seq/wave, 1024 waves = 1/SIMD):
//   l32 = L*16 + j*2 + p    L=layer(bit4), j=unit(bits1-3), p=gate-pair(bit0)
// Lane (L,j,p) owns gate rows rA=p*16+j (i or g~) and rB=p*16+8+j (f or o),
// computing FULL 8-k dots (h gathered via 9 DPP ops, no LDS on the chain).
// Activations split across the p pair (p=0: sig(i),sig(f); p=1: tanh(g),
// sig(o)), shared back by quad_perm xor1 DPP (round-3-proven scheme).
//
// Deepened pipeline: iter t computes L0(t) and L1(t-2). L1's input-dot
// (W_ih1 . h1) is computed on L0 lanes one full iteration before L1
// consumes it, crossing the 16-lane boundary via 2 xor16 ds_swizzles
// whose ~120cyc latency is hidden by the ~200cyc iteration.
// Projection (W_lin . h2) rides L1 lanes' spare dot slot.
// Gates pre-scaled by -log2e (tanh rows -2log2e): act = rcp(1+exp2(z)).

constexpr int Bsz = 2048;
constexpr int Tsz = 4096;

typedef float v2f __attribute__((ext_vector_type(2)));

__device__ __forceinline__ void pk_fma(v2f& acc, v2f a, v2f b) {
    asm("v_pk_fma_f32 %0, %1, %2, %0" : "+v"(acc) : "v"(a), "v"(b));
}

template <int CTRL>
__device__ __forceinline__ float dpp(float v) {
    return __int_as_float(
        __builtin_amdgcn_mov_dpp(__float_as_int(v), CTRL, 0xF, 0xF, true));
}
// ctrl codes: quad_perm xor1=0xB1, xor2=0x4E, xor3=0x1B;
//             row_half_mirror(xor7)=0x141, row_mirror(xor15)=0x140

__device__ __forceinline__ float swz16(float v) {
    // ds_swizzle bit mode, xor 0x10: offset = (0x10<<10)|0x1f
    return __int_as_float(
        __builtin_amdgcn_ds_swizzle(__float_as_int(v), 0x401F));
}

__global__ void __launch_bounds__(256) lstm2_dpp(
    const float* __restrict__ x,      // [B, T]
    const float* __restrict__ Wih0,   // [32, 1]
    const float* __restrict__ Whh0,   // [32, 8]
    const float* __restrict__ bih0,   // [32]
    const float* __restrict__ bhh0,   // [32]
    const float* __restrict__ Wih1,   // [32, 8]
    const float* __restrict__ Whh1,   // [32, 8]
    const float* __restrict__ bih1,   // [32]
    const float* __restrict__ bhh1,   // [32]
    const float* __restrict__ Wlin,   // [1, 8]
    const float* __restrict__ blin,   // [1]
    float* __restrict__ out)          // [B, T]
{
    const int tid  = threadIdx.x;
    const int l32  = tid & 31;
    const int p    = l32 & 1;
    const int j    = (l32 >> 1) & 7;
    const int L    = (l32 >> 4) & 1;
    const bool pb  = (p != 0);
    const int seq  = blockIdx.x * 8 + (tid >> 5);

    const int rA = p * 16 + j;        // p=0: i-row; p=1: g-row (tanh)
    const int rB = p * 16 + 8 + j;    // p=0: f-row; p=1: o-row

    const float NL2E  = -1.4426950408889634f;   // -log2(e)
    const float N2L2E = -2.8853900817779268f;   // -2*log2(e)
    const float wsA = pb ? N2L2E : NL2E;
    const float wsB = NL2E;
    const float sA  = pb ? 2.0f : 1.0f;         // tanh = 2*sig(2z)-1
    const float oA  = pb ? -1.0f : 0.0f;

    const float* __restrict__ Whh = L ? Whh1 : Whh0;
    const float* __restrict__ bih = L ? bih1 : bih0;
    const float* __restrict__ bhh = L ? bhh1 : bhh0;

    // slot q: hp[q].x <-> k=j^(2q), hp[q].y <-> k=j^(2q+1)
    v2f wp1A[4], wp1B[4], wp2A[4], wp2B[4];
#pragma unroll
    for (int q = 0; q < 4; ++q) {
        const int kx = j ^ (2 * q);
        const int ky = j ^ (2 * q + 1);
        wp1A[q] = v2f{Whh[rA * 8 + kx] * wsA, Whh[rA * 8 + ky] * wsA};
        wp1B[q] = v2f{Whh[rB * 8 + kx] * wsB, Whh[rB * 8 + ky] * wsB};
        if (L) {  // L1 spare dot = projection (row A), zero (row B)
            wp2A[q] = v2f{Wlin[kx], Wlin[ky]};
            wp2B[q] = v2f{0.0f, 0.0f};
        } else {  // L0 spare dot = W_ih1 rows for the partner L1 lane
            wp2A[q] = v2f{Wih1[rA * 8 + kx] * wsA, Wih1[rA * 8 + ky] * wsA};
            wp2B[q] = v2f{Wih1[rB * 8 + kx] * wsB, Wih1[rB * 8 + ky] * wsB};
        }
    }
    const float wxA   = L ? 0.0f : Wih0[rA] * wsA;
    const float wxB   = L ? 0.0f : Wih0[rB] * wsB;
    const float biasA = (bih[rA] + bhh[rA]) * wsA;
    const float biasB = (bih[rB] + bhh[rB]) * wsB;
    const float b2A   = L ? blin[0] : 0.0f;   // proj bias on L1 lanes
    const float mL    = L ? 1.0f : 0.0f;      // consume recv only on L1
    const float keep  = 1.0f - mL;

    const float* __restrict__ xp = x + (size_t)seq * Tsz;
    float* __restrict__ op       = out + (size_t)seq * Tsz;
    const bool storeLane = (l32 == 16);

    v2f hp[4];
#pragma unroll
    for (int q = 0; q < 4; ++q) hp[q] = v2f{0.0f, 0.0f};
    float c = 0.0f, h = 0.0f;
    float recvA = 0.0f, recvB = 0.0f;

    float xn1 = xp[0];
    float xn2 = xp[1];

    auto body = [&](int t) {
        const float xt = xn1;
        xn1 = xn2;
        int ti = t + 2; ti = (ti < Tsz) ? ti : (Tsz - 1);
        xn2 = xp[ti];

        // ---- dots over hp (prev-iter gather): dot1 = own hh; dot2 = spare
        v2f a1A = v2f{fmaf(wxA, xt, biasA), 0.0f};
        v2f a1B = v2f{fmaf(wxB, xt, biasB), 0.0f};
        v2f a2A = v2f{b2A, 0.0f};
        v2f a2B = v2f{0.0f, 0.0f};
#pragma unroll
        for (int q = 0; q < 4; ++q) {
            pk_fma(a1A, wp1A[q], hp[q]);
            pk_fma(a1B, wp1B[q], hp[q]);
            pk_fma(a2A, wp2A[q], hp[q]);
            pk_fma(a2B, wp2B[q], hp[q]);
        }
        const float d1A = a1A.x + a1A.y;
        const float d1B = a1B.x + a1B.y;
        const float d2A = a2A.x + a2A.y;
        const float d2B = a2B.x + a2B.y;

        // store proj (L1 lane j=0,p=0 has full W_lin.h2(t-3)+blin in d2A)
        if (t >= 3 && storeLane) op[t - 3] = d2A;

        // consume last iter's cross-layer dot; launch this iter's (hidden
        // behind a full iteration before use)
        const float rAo = recvA, rBo = recvB;
        recvA = swz16(d2A);
        recvB = swz16(d2B);

        const float zA = fmaf(mL, rAo, d1A);
        const float zB = fmaf(mL, rBo, d1B);

        // ---- activations split across p pair, shared via xor1 DPP
        float aA = fmaf(sA,
                        __builtin_amdgcn_rcpf(1.0f + __builtin_amdgcn_exp2f(zA)),
                        oA);                     // p0: sig(i); p1: tanh(g)
        float aB = __builtin_amdgcn_rcpf(1.0f + __builtin_amdgcn_exp2f(zB));
        const float xA = dpp<0xB1>(aA);
        const float xB = dpp<0xB1>(aB);
        const float gi = pb ? xA : aA;
        const float gg = pb ? aA : xA;
        const float gf = pb ? xB : aB;
        const float go = pb ? aB : xB;
        c = fmaf(gf, c, gi * gg);
        const float e  = __builtin_amdgcn_exp2f(c * N2L2E);
        const float th = fmaf(2.0f, __builtin_amdgcn_rcpf(1.0f + e), -1.0f);
        h = go * th;

        // ---- h all-gather within the 16-lane half: 9 DPP, depth 3
        const float g0  = h;                 // k=j
        const float g2  = dpp<0x4E>(h);      // ^2  -> j^1
        const float mB  = dpp<0x141>(h);     // ^7
        const float g4  = dpp<0x1B>(mB);     // ^7^3 = ^4 -> j^2
        const float g6  = dpp<0xB1>(mB);     // ^7^1 = ^6 -> j^3
        const float mC  = dpp<0x140>(h);     // ^15
        const float g12 = dpp<0x1B>(mC);     // ^15^3 = ^12 -> j^6
        const float g14 = dpp<0xB1>(mC);     // ^15^1 = ^14 -> j^7
        const float g8  = dpp<0x141>(mC);    // ^15^7 = ^8  -> j^4
        const float g10 = dpp<0x4E>(g8);     // ^8^2  = ^10 -> j^5
        hp[0] = v2f{g0, g2};
        hp[1] = v2f{g4, g6};
        hp[2] = v2f{g8, g10};
        hp[3] = v2f{g12, g14};
    };

    // ---- pipeline fill: L1 state must be zero entering iter 2 (step 0)
    body(0);
    h *= keep; c *= keep;
#pragma unroll
    for (int q = 0; q < 4; ++q) { hp[q].x *= keep; hp[q].y *= keep; }
    body(1);
    h *= keep; c *= keep;
#pragma unroll
    for (int q = 0; q < 4; ++q) { hp[q].x *= keep; hp[q].y *= keep; }

    // ---- main loop: iter t: L0(t), L1(t-2), store out[t-3]
    for (int t = 2; t <= Tsz + 2; ++t) body(t);
}

extern "C" void kernel_launch(void* const* d_in, const int* in_sizes, int n_in,
                              void* d_out, int out_size, void* d_ws, size_t ws_size,
                              hipStream_t stream) {
    const float* x    = (const float*)d_in[0];
    const float* Wih0 = (const float*)d_in[1];
    const float* Whh0 = (const float*)d_in[2];
    const float* bih0 = (const float*)d_in[3];
    const float* bhh0 = (const float*)d_in[4];
    const float* Wih1 = (const float*)d_in[5];
    const float* Whh1 = (const float*)d_in[6];
    const float* bih1 = (const float*)d_in[7];
    const float* bhh1 = (const float*)d_in[8];
    const float* Wlin = (const float*)d_in[9];
    const float* blin = (const float*)d_in[10];
    float* out = (float*)d_out;

    dim3 grid(Bsz / 8);   // 8 sequences per 256-thread block (2 per wave)
    dim3 block(256);
    hipLaunchKernelGGL(lstm2_dpp, grid, block, 0, stream,
                       x, Wih0, Whh0, bih0, bhh0,
                       Wih1, Whh1, bih1, bhh1, Wlin, blin, out);
}

// Round 5
// 948.532 us; speedup vs baseline: 1.2102x; 1.0587x over previous
//
#include <hip/hip_runtime.h>

// 2-layer LSTM, B=2048, T=4096, IN=1, H=8, OUT=1, fp32.
//
// Quad-64 layout: ONE sequence per wave64, lane = L*32 + j*4 + g
//   (L=layer bit5, j=unit bits2-4, g=gate 0..3: i,f,g~,o).
// 2048 seqs -> 2048 waves -> 2 waves/SIMD on 1024 SIMDs: two independent
// recurrence chains per SIMD fill each other's dependency stalls (the R4
// structure was 1 wave/SIMD and measured 54% idle at 46% VALUBusy).
//
// Each lane owns gate row r = g*8+j of its layer: full 8-k dot = 4 pk_fma.
// Gate exchange: 4 quad_perm broadcasts (DPP) -> all lanes compute the
// cell redundantly (no selects). h-gather: j^1..j^3 via 5 DPPs
// (xor4=7o3, xor8=15o7, xor12=15o3), j^4..j^7 via 4 independent
// ds_swizzles (xor16/20/24/28) feeding the LAST dot slots.
// Cross-layer: L1 runs 2 steps behind L0; L0 lanes' spare dot computes
// Wih1 . h1, shipped via one wave-wide ds_bpermute (lane^32), consumed
// one full iteration later (latency off-chain). Projection = L1 lanes'
// spare dot (Wlin . h2 + blin), stored from lane 32.
// Rows pre-scaled by -log2e (g~ rows -2log2e): act = rcp(1+exp2(z)).

constexpr int Bsz = 2048;
constexpr int Tsz = 4096;

typedef float v2f __attribute__((ext_vector_type(2)));

__device__ __forceinline__ void pk_fma(v2f& acc, v2f a, v2f b) {
    asm("v_pk_fma_f32 %0, %1, %2, %0" : "+v"(acc) : "v"(a), "v"(b));
}

template <int CTRL>
__device__ __forceinline__ float dpp(float v) {
    return __int_as_float(
        __builtin_amdgcn_mov_dpp(__float_as_int(v), CTRL, 0xF, 0xF, true));
}
// quad_perm bcast0..3 = 0x00,0x55,0xAA,0xFF; quad xor3 = 0x1B;
// row_half_mirror (xor7) = 0x141; row_mirror (xor15) = 0x140

template <int XORM>
__device__ __forceinline__ float swz(float v) {
    // ds_swizzle bit mode: pure xor within each 32-lane group
    return __int_as_float(
        __builtin_amdgcn_ds_swizzle(__float_as_int(v), (XORM << 10) | 0x1f));
}

__device__ __forceinline__ float bperm(int addr, float v) {
    return __int_as_float(
        __builtin_amdgcn_ds_bpermute(addr, __float_as_int(v)));
}

__global__ void __launch_bounds__(256, 2) lstm2_q64(
    const float* __restrict__ x,      // [B, T]
    const float* __restrict__ Wih0,   // [32, 1]
    const float* __restrict__ Whh0,   // [32, 8]
    const float* __restrict__ bih0,   // [32]
    const float* __restrict__ bhh0,   // [32]
    const float* __restrict__ Wih1,   // [32, 8]
    const float* __restrict__ Whh1,   // [32, 8]
    const float* __restrict__ bih1,   // [32]
    const float* __restrict__ bhh1,   // [32]
    const float* __restrict__ Wlin,   // [1, 8]
    const float* __restrict__ blin,   // [1]
    float* __restrict__ out)          // [B, T]
{
    const int tid  = threadIdx.x;
    const int lane = tid & 63;
    const int g    = lane & 3;
    const int j    = (lane >> 2) & 7;
    const int L    = (lane >> 5) & 1;
    const int seq  = blockIdx.x * 4 + (tid >> 6);   // 1 seq per wave

    const int r = g * 8 + j;          // gate row (PyTorch order i,f,g~,o)

    const float NL2E  = -1.4426950408889634f;   // -log2(e)
    const float N2L2E = -2.8853900817779268f;   // -2*log2(e)
    const bool  isG   = (g == 2);
    const float ws    = isG ? N2L2E : NL2E;
    const float sA    = isG ? 2.0f : 1.0f;      // tanh = 2*sig(2z)-1
    const float oA    = isG ? -1.0f : 0.0f;

    const float* __restrict__ Whh = L ? Whh1 : Whh0;
    const float* __restrict__ bih = L ? bih1 : bih0;
    const float* __restrict__ bhh = L ? bhh1 : bhh0;

    // wp1: own hh row; wp2: spare dot (L0: Wih1 row r for partner L1 lane,
    // L1: Wlin for the projection). Slot q pairs k = j^(2q), j^(2q+1).
    v2f wp1[4], wp2[4];
#pragma unroll
    for (int q = 0; q < 4; ++q) {
        const int kx = j ^ (2 * q);
        const int ky = j ^ (2 * q + 1);
        wp1[q] = v2f{Whh[r * 8 + kx] * ws, Whh[r * 8 + ky] * ws};
        wp2[q] = L ? v2f{Wlin[kx], Wlin[ky]}
                   : v2f{Wih1[r * 8 + kx] * ws, Wih1[r * 8 + ky] * ws};
    }
    const float bias = (bih[r] + bhh[r]) * ws;
    const float wx   = L ? 0.0f : Wih0[r] * ws;
    const float b2   = L ? blin[0] : 0.0f;
    const float mL   = L ? 1.0f : 0.0f;   // consume shipped dot only on L1
    const float keep = 1.0f - mL;
    const int  xaddr = (lane ^ 32) * 4;   // bpermute: swap layer halves

    const float* __restrict__ xp = x + (size_t)seq * Tsz;
    float* __restrict__ op       = out + (size_t)seq * Tsz;
    const bool storeLane = (lane == 32);  // L1, j=0, g=0

    v2f hp[4];
#pragma unroll
    for (int q = 0; q < 4; ++q) hp[q] = v2f{0.0f, 0.0f};
    float c = 0.0f, h = 0.0f, recv = 0.0f;

    float xn1 = xp[0];
    float xn2 = xp[1];

    auto body = [&](int t) {
        const float xt = xn1;
        xn1 = xn2;
        int ti = t + 2; ti = (ti < Tsz) ? ti : (Tsz - 1);
        xn2 = xp[ti];

        // dots over hp (own-layer h from prev iter's gather)
        v2f a1 = v2f{fmaf(wx, xt, bias), 0.0f};
        v2f a2 = v2f{b2, 0.0f};
#pragma unroll
        for (int q = 0; q < 4; ++q) {
            pk_fma(a1, wp1[q], hp[q]);
            pk_fma(a2, wp2[q], hp[q]);
        }
        const float d1 = a1.x + a1.y;
        const float d2 = a2.x + a2.y;

        // projection store: L1 lane32's d2 = blin + Wlin . h2(t-3)
        if (t >= 3 && storeLane) op[t - 3] = d2;

        // consume last iter's cross-layer dot, ship this iter's
        const float rOld = recv;
        recv = bperm(xaddr, d2);      // L1 pulls L0's Wih1 . h1(t-1)

        const float z = fmaf(mL, rOld, d1);
        // gate activation (row pre-scaled): sig or tanh via fma
        float a = fmaf(sA,
                       __builtin_amdgcn_rcpf(1.0f + __builtin_amdgcn_exp2f(z)),
                       oA);
        // quad broadcast: all 4 gates of unit j to every lane of the quad
        const float gi = dpp<0x00>(a);
        const float gf = dpp<0x55>(a);
        const float gG = dpp<0xAA>(a);
        const float go = dpp<0xFF>(a);
        c = fmaf(gf, c, gi * gG);
        const float e  = __builtin_amdgcn_exp2f(c * N2L2E);
        const float th = fmaf(2.0f, __builtin_amdgcn_rcpf(1.0f + e), -1.0f);
        h = go * th;   // every lane of quad j holds h[j] (redundant x4)

        // h all-gather within the 32-lane layer half
        const float m7  = dpp<0x141>(h);    // ^7
        const float h1_ = dpp<0x1B>(m7);    // ^7^3 = ^4  -> j^1
        const float m15 = dpp<0x140>(h);    // ^15
        const float h2_ = dpp<0x141>(m15);  // ^15^7 = ^8 -> j^2
        const float h3_ = dpp<0x1B>(m15);   // ^15^3 = ^12 -> j^3
        const float h4_ = swz<16>(h);       // j^4
        const float h5_ = swz<20>(h);       // j^5
        const float h6_ = swz<24>(h);       // j^6
        const float h7_ = swz<28>(h);       // j^7
        hp[0] = v2f{h,   h1_};
        hp[1] = v2f{h2_, h3_};
        hp[2] = v2f{h4_, h5_};   // swizzle-fed: last dot slots next iter
        hp[3] = v2f{h6_, h7_};
    };

    // pipeline fill: L1 state must be zero entering the steady loop
    body(0);
    h *= keep; c *= keep;
#pragma unroll
    for (int q = 0; q < 4; ++q) { hp[q].x *= keep; hp[q].y *= keep; }
    body(1);
    h *= keep; c *= keep;
#pragma unroll
    for (int q = 0; q < 4; ++q) { hp[q].x *= keep; hp[q].y *= keep; }

    // steady: iter t computes L0(t), L1(t-2), stores out[t-3]
    for (int t = 2; t <= Tsz + 2; ++t) body(t);
}

extern "C" void kernel_launch(void* const* d_in, const int* in_sizes, int n_in,
                              void* d_out, int out_size, void* d_ws, size_t ws_size,
                              hipStream_t stream) {
    const float* x    = (const float*)d_in[0];
    const float* Wih0 = (const float*)d_in[1];
    const float* Whh0 = (const float*)d_in[2];
    const float* bih0 = (const float*)d_in[3];
    const float* bhh0 = (const float*)d_in[4];
    const float* Wih1 = (const float*)d_in[5];
    const float* Whh1 = (const float*)d_in[6];
    const float* bih1 = (const float*)d_in[7];
    const float* bhh1 = (const float*)d_in[8];
    const float* Wlin = (const float*)d_in[9];
    const float* blin = (const float*)d_in[10];
    float* out = (float*)d_out;

    dim3 grid(Bsz / 4);   // 4 waves/block, 1 seq/wave -> 512 blocks, 2048 waves
    dim3 block(256);
    hipLaunchKernelGGL(lstm2_q64, grid, block, 0, stream,
                       x, Wih0, Whh0, bih0, bhh0,
                       Wih1, Whh1, bih1, bhh1, Wlin, blin, out);
}